// Round 11
// baseline (385.216 us; speedup 1.0000x reference)
//
#include <hip/hip_runtime.h>
#include <stdint.h>

#define N_NODES 50000
#define N_EDGES 800000
#define NODE_TILES 782              // ceil(50000/64)

#define SE   72    // e-tile stride (bf16); message tile ALIASES this buffer
#define SW2  72
#define SPQ  136   // pq kernel strides (K=128)
#define SN1  216   // Wn1T row stride (K=192) -- dword 108 == 12 mod 32: 2-way
#define SN2  280   // Wn2T row stride (K=256) -- dword 140 == 12 mod 32: 2-way
#define ATS  40    // edge A-tile row stride (dword 20: 2-way, 16B-aligned)

#define EC_GRID 1563  // 1563*4 waves * 8 tiles = 50016 >= 50000 (6 blk/CU capacity)
#define EC_CHUNK 8

#define SCAN_B 98     // 98*512 = 50176 >= 50000

typedef short bf16x8 __attribute__((ext_vector_type(8)));
typedef short short4v __attribute__((ext_vector_type(4)));
typedef unsigned short ushort8 __attribute__((ext_vector_type(8)));
typedef unsigned int uint4v __attribute__((ext_vector_type(4)));
typedef float f32x4  __attribute__((ext_vector_type(4)));

static __device__ __forceinline__ unsigned short f2bf(float f) {
  unsigned int x = __float_as_uint(f);
  unsigned int r = (x + 0x7fffu + ((x >> 16) & 1u)) >> 16;
  return (unsigned short)r;
}
static __device__ __forceinline__ float bf2f(unsigned short u) {
  return __uint_as_float(((unsigned int)u) << 16);
}
static __device__ __forceinline__ float silu_f(float x) {
  return x * __builtin_amdgcn_rcpf(1.0f + __expf(-x));
}
static __device__ __forceinline__ float sigmoid_f(float x) {
  return __builtin_amdgcn_rcpf(1.0f + __expf(-x));
}
static __device__ __forceinline__ unsigned int cvt_pk_bf16(float lo, float hi) {
  unsigned int r;
  asm("v_cvt_pk_bf16_f32 %0, %1, %2" : "=v"(r) : "v"(lo), "v"(hi));
  return r;
}
static __device__ __forceinline__ bf16x8 pack8(float4 u, float4 v) {
  bf16x8 w;
  w[0] = (short)f2bf(u.x); w[1] = (short)f2bf(u.y);
  w[2] = (short)f2bf(u.z); w[3] = (short)f2bf(u.w);
  w[4] = (short)f2bf(v.x); w[5] = (short)f2bf(v.y);
  w[6] = (short)f2bf(v.z); w[7] = (short)f2bf(v.w);
  return w;
}

// ---------------------------------------------------------------------------
// prep: natural transposed bf16 weights + destination histogram.
// ---------------------------------------------------------------------------
__global__ void prep_hist(
    const int* __restrict__ eidx,
    const float* __restrict__ We1, const float* __restrict__ be1,
    const float* __restrict__ We2,
    const float* __restrict__ Wn1, const float* __restrict__ Wn2,
    unsigned short* __restrict__ WpqT, unsigned short* __restrict__ We2T,
    unsigned short* __restrict__ Wn1T, unsigned short* __restrict__ Wn2T,
    unsigned short* __restrict__ WrT,
    int* __restrict__ cnt)
{
  const int gid = blockIdx.x * 256 + threadIdx.x;
  const int gsz = gridDim.x * 256;
  for (int i = gid; i < 128 * SPQ; i += gsz) {
    int n = i / SPQ, k = i % SPQ;
    unsigned short v = 0;
    if (k < 128) v = (n < 64) ? f2bf(We1[k * 64 + n]) : f2bf(We1[(128 + k) * 64 + (n - 64)]);
    WpqT[i] = v;
  }
  for (int i = gid; i < 64 * SW2; i += gsz) {
    int n = i / SW2, k = i % SW2;
    We2T[i] = (k < 64) ? f2bf(We2[k * 64 + n]) : (unsigned short)0;
  }
  for (int i = gid; i < 256 * SN1; i += gsz) {
    int n = i / SN1, k = i % SN1;
    Wn1T[i] = (k < 192) ? f2bf(Wn1[k * 256 + n]) : (unsigned short)0;
  }
  for (int i = gid; i < 128 * SN2; i += gsz) {
    int n = i / SN2, k = i % SN2;
    Wn2T[i] = (k < 256) ? f2bf(Wn2[k * 128 + n]) : (unsigned short)0;
  }
  for (int i = gid; i < 64 * 32; i += gsz) {
    int n = i >> 5, k = i & 31;
    float v = 0.f;
    if (k < 2)       v = We1[256 * 64 + n];
    else if (k < 4)  v = We1[257 * 64 + n];
    else if (k < 12) v = We1[(258 + (k - 4)) * 64 + n];
    else if (k == 12) v = be1[n];
    else if (k == 13) { float w = We1[256 * 64 + n]; v = w - bf2f(f2bf(w)); }
    else if (k == 14) { float w = We1[257 * 64 + n]; v = w - bf2f(f2bf(w)); }
    else if (k == 15) { float w = be1[n];            v = w - bf2f(f2bf(w)); }
    WrT[i] = (k < 16) ? f2bf(v) : (unsigned short)0;
  }
  if (gid < N_EDGES) atomicAdd(&cnt[eidx[gid]], 1);
}

// ---------------------------------------------------------------------------
// hierarchical scan (coalesced, no per-thread arrays)
// ---------------------------------------------------------------------------
__global__ __launch_bounds__(512) void scan_local(
    const int* __restrict__ cnt, int* __restrict__ rowptr,
    int* __restrict__ bsum)
{
  __shared__ int wsum[8], woff[8];
  const int t = threadIdx.x;
  const int idx = blockIdx.x * 512 + t;
  const int lane = t & 63, wid = t >> 6;
  int c = (idx < N_NODES) ? cnt[idx] : 0;
  int v = c;
  #pragma unroll
  for (int o = 1; o < 64; o <<= 1) {
    int u = __shfl_up(v, o);
    if (lane >= o) v += u;
  }
  if (lane == 63) wsum[wid] = v;
  __syncthreads();
  if (t == 0) {
    int a = 0;
    #pragma unroll
    for (int w = 0; w < 8; ++w) { woff[w] = a; a += wsum[w]; }
    bsum[blockIdx.x] = a;
  }
  __syncthreads();
  if (idx < N_NODES) rowptr[idx] = woff[wid] + (v - c);
}

__global__ __launch_bounds__(128) void scan_mid(
    const int* __restrict__ bsum, int* __restrict__ boff)
{
  __shared__ int ws[2];
  const int t = threadIdx.x;
  const int lane = t & 63, wid = t >> 6;
  int c = (t < SCAN_B) ? bsum[t] : 0;
  int v = c;
  #pragma unroll
  for (int o = 1; o < 64; o <<= 1) {
    int u = __shfl_up(v, o);
    if (lane >= o) v += u;
  }
  if (lane == 63) ws[wid] = v;
  __syncthreads();
  int add = (wid == 1) ? ws[0] : 0;
  if (t < SCAN_B) boff[t] = add + (v - c);
}

// scan_add also zeroes agg (folds the 12.8 MB memset dispatch away)
__global__ __launch_bounds__(512) void scan_add(
    const int* __restrict__ rowptr, const int* __restrict__ boff,
    int* __restrict__ cursor, float4* __restrict__ agg)
{
  const int idx = blockIdx.x * 512 + threadIdx.x;
  if (idx < N_NODES) cursor[idx] = rowptr[idx] + boff[blockIdx.x];
  if (idx < 50048) {
    float4 z = make_float4(0.f, 0.f, 0.f, 0.f);
    float4* p = agg + (long)idx * 16;
    #pragma unroll
    for (int k = 0; k < 16; ++k) p[k] = z;
  }
}

// ---------------------------------------------------------------------------
// fill_reorder: one thread per edge, coalesced reads, gate MLP, ONE 32-B
// record scattered to rec[pos] via NON-TEMPORAL stores (rec is produce-once/
// consume-next-kernel; nt avoids L2 allocate on the random scatter).
// Record: [0:8) d2h,d2l,dlh,dll  [8:24) struct bf16  [24:28) g  [28:32) i|j<<16
// ---------------------------------------------------------------------------
__global__ void fill_reorder(
    const int* __restrict__ eidx, const float* __restrict__ xyz,
    const float* __restrict__ estruct, const float* __restrict__ erest,
    int* __restrict__ cursor,
    const float* __restrict__ Wg1, const float* __restrict__ bg1,
    const float* __restrict__ Wg2, const float* __restrict__ bg2,
    unsigned short* __restrict__ rec)
{
  int e = blockIdx.x * 256 + threadIdx.x;
  if (e >= N_EDGES) return;
  int i = eidx[e], j = eidx[N_EDGES + e];
  float dx = xyz[i * 3 + 0] - xyz[j * 3 + 0];
  float dy = xyz[i * 3 + 1] - xyz[j * 3 + 1];
  float dz = xyz[i * 3 + 2] - xyz[j * 3 + 2];
  float d2 = dx * dx + dy * dy + dz * dz;
  float dist = sqrtf(d2 + 1e-9f);
  float rest = erest[e];
  float dl = (dist - rest) / (rest + 1e-9f);
  float4 s0 = *(const float4*)&estruct[e * 8];
  float4 s1 = *(const float4*)&estruct[e * 8 + 4];
  float st[8] = {s0.x, s0.y, s0.z, s0.w, s1.x, s1.y, s1.z, s1.w};
  float gsum = 0.f;
  #pragma unroll
  for (int h = 0; h < 32; ++h) {
    float a = bg1[h] + d2 * Wg1[0 * 32 + h] + dl * Wg1[1 * 32 + h];
    #pragma unroll
    for (int c = 0; c < 8; ++c) a += st[c] * Wg1[(2 + c) * 32 + h];
    gsum += silu_f(a) * Wg2[h];
  }
  float g = sigmoid_f(gsum + bg2[0]);

  unsigned short d2h = f2bf(d2);
  unsigned short d2l = f2bf(d2 - bf2f(d2h));
  unsigned short dlh = f2bf(dl);
  unsigned short dll = f2bf(dl - bf2f(dlh));

  ushort8 w0;
  w0[0] = d2h; w0[1] = d2l; w0[2] = dlh; w0[3] = dll;
  w0[4] = f2bf(st[0]); w0[5] = f2bf(st[1]); w0[6] = f2bf(st[2]); w0[7] = f2bf(st[3]);
  uint4v w1;
  w1[0] = (unsigned int)f2bf(st[4]) | ((unsigned int)f2bf(st[5]) << 16);
  w1[1] = (unsigned int)f2bf(st[6]) | ((unsigned int)f2bf(st[7]) << 16);
  w1[2] = __float_as_uint(g);
  w1[3] = (unsigned int)i | ((unsigned int)j << 16);

  int pos = atomicAdd(&cursor[i], 1);
  unsigned short* dst = rec + (long)pos * 16;
  uint4v a0 = *(uint4v*)&w0;
  __builtin_nontemporal_store(a0, (uint4v*)dst);
  __builtin_nontemporal_store(w1, (uint4v*)(dst + 8));
}

// ---------------------------------------------------------------------------
// pq: standalone, LDS-free A-path. Stage only Ws (34.8 KB) + one barrier;
// each of 4 waves computes 16 rows, loading H fragments directly
// (f32 -> pack8 -> Hbf export inline). Grid = NODE_TILES.
// ---------------------------------------------------------------------------
__global__ __launch_bounds__(256, 4) void pq_kernel(
    const float* __restrict__ H, const unsigned short* __restrict__ WpqT,
    unsigned short* __restrict__ P, unsigned short* __restrict__ Q,
    unsigned short* __restrict__ Hbf)
{
  __shared__ unsigned short Ws[128 * SPQ];   // 34.8 KB (only LDS)

  const int tid  = threadIdx.x;
  const int lane = tid & 63;
  const int wv   = tid >> 6;
  const int lr   = lane & 15;
  const int lq   = lane >> 4;
  const int n0   = blockIdx.x * 64;
  const int m0   = wv * 16;

  for (int i = tid * 8; i < 128 * SPQ; i += 256 * 8)
    *(bf16x8*)&Ws[i] = *(const bf16x8*)&WpqT[i];
  __syncthreads();

  const int rowa = n0 + m0 + lr;
  const int rowc = rowa < N_NODES ? rowa : N_NODES - 1;

  f32x4 zero4 = {0.f, 0.f, 0.f, 0.f};
  f32x4 acc[8];
  #pragma unroll
  for (int f = 0; f < 8; ++f) acc[f] = zero4;

  #pragma unroll
  for (int s = 0; s < 4; ++s) {
    int kb = s * 32 + lq * 8;
    const float* p = H + (long)rowc * 128 + kb;
    float4 u = *(const float4*)p;
    float4 v = *(const float4*)(p + 4);
    bf16x8 a = pack8(u, v);
    *(bf16x8*)&Hbf[(long)rowa * 128 + kb] = a;   // export (each (row,kb) once)
    #pragma unroll
    for (int f = 0; f < 8; ++f) {
      bf16x8 b = *(const bf16x8*)&Ws[(f * 16 + lr) * SPQ + kb];
      acc[f] = __builtin_amdgcn_mfma_f32_16x16x32_bf16(a, b, acc[f], 0, 0, 0);
    }
  }
  #pragma unroll
  for (int f = 0; f < 8; ++f) {
    #pragma unroll
    for (int r = 0; r < 4; ++r) {
      int node = n0 + m0 + lq * 4 + r;
      if (node < N_NODES) {
        if (f < 4) P[(long)node * 64 + f * 16 + lr] = f2bf(acc[f][r]);
        else       Q[(long)node * 64 + (f - 4) * 16 + lr] = f2bf(acc[f][r]);
      }
    }
  }
}

// ---------------------------------------------------------------------------
// edge_compute (R16): occupancy fix. The message tile ALIASES the Es buffer
// (Es fully consumed by GEMM2 before the epilogue rewrites it; same-wave DS
// ops execute in order) -> LDS 32.7 -> 23.5 KB -> 6 blocks/CU. EC_CHUNK 8 /
// grid 1563 fills the new capacity. Segsum + record path unchanged.
// ---------------------------------------------------------------------------
__global__ __launch_bounds__(256, 6) void edge_compute(
    const unsigned short* __restrict__ P, const unsigned short* __restrict__ Q,
    const unsigned short* __restrict__ rec,
    const unsigned short* __restrict__ We2T, const float* __restrict__ be2,
    const unsigned short* __restrict__ WrT,
    float* __restrict__ agg)
{
  __shared__ unsigned short W2s[64 * SW2];       // 9.2 KB
  __shared__ unsigned short Es [4 * 16 * SE];    // 9.2 KB (also message tile)
  __shared__ unsigned short At [4 * 16 * ATS];   // 5.1 KB  (23.5 KB total)

  const int tid  = threadIdx.x;
  const int lane = tid & 63;
  const int wv   = tid >> 6;
  const int lr   = lane & 15;
  const int lq   = lane >> 4;

  for (int i = tid * 8; i < 64 * SW2; i += 256 * 8)
    *(bf16x8*)&W2s[i] = *(const bf16x8*)&We2T[i];

  unsigned short* Es_w = &Es[wv * 16 * SE];
  unsigned short* At_w = &At[wv * 16 * ATS];

  if (lane < 16) {
    ushort8 z;
    #pragma unroll
    for (int c = 0; c < 8; ++c) z[c] = 0;
    *(ushort8*)&At_w[lane * ATS + 16] = z;
    *(ushort8*)&At_w[lane * ATS + 24] = z;
  }

  bf16x8 aWr[4];
  float bias2[4][4];
  #pragma unroll
  for (int f = 0; f < 4; ++f) {
    aWr[f] = *(const bf16x8*)&WrT[(f * 16 + lr) * 32 + lq * 8];
    #pragma unroll
    for (int r = 0; r < 4; ++r) bias2[f][r] = be2[f * 16 + lq * 4 + r];
  }
  __syncthreads();

  const int n_tiles = N_EDGES / 16;  // 50000
  const int wid = blockIdx.x * 4 + wv;
  const int t0 = wid * EC_CHUNK;
  const int t1 = (t0 + EC_CHUNK < n_tiles) ? (t0 + EC_CHUNK) : n_tiles;
  if (t0 >= n_tiles) return;

  f32x4 zero4 = {0.f, 0.f, 0.f, 0.f};
  int   cur_node;
  {
    int ij0 = *(const int*)(rec + (long)t0 * 16 * 16 + 14);
    cur_node = ij0 & 0xffff;
  }
  float acc        = 0.f;
  bool  use_atomic = true;

  for (int tile = t0; tile < t1; ++tile) {
    const int s0 = tile * 16;

    const unsigned short* rp = rec + (long)(s0 + lr) * 16;
    ushort8 ra = *(const ushort8*)rp;          // d2h,d2l,dlh,dll,st0..3
    uint4   rb = *(const uint4*)(rp + 8);      // st4..7 | g | i,j
    float g     = __uint_as_float(rb.z);
    int   inode = (int)(rb.w & 0xffff);
    int   jnode = (int)((rb.w >> 16) & 0xffff);

    if (lane < 16) {
      ushort8 w1;
      w1[0] = (unsigned short)(rb.x & 0xffff);
      w1[1] = (unsigned short)(rb.x >> 16);
      w1[2] = (unsigned short)(rb.y & 0xffff);
      w1[3] = (unsigned short)(rb.y >> 16);
      w1[4] = 0x3F80u; w1[5] = (unsigned short)ra[0];
      w1[6] = (unsigned short)ra[2]; w1[7] = 0x3F80u;
      *(ushort8*)&At_w[lane * ATS]     = ra;
      *(ushort8*)&At_w[lane * ATS + 8] = w1;
    }

    bf16x8 bA = *(const bf16x8*)&At_w[lr * ATS + lq * 8];
    f32x4 acc1[4];
    #pragma unroll
    for (int f = 0; f < 4; ++f)
      acc1[f] = __builtin_amdgcn_mfma_f32_16x16x32_bf16(aWr[f], bA, zero4, 0, 0, 0);

    const unsigned short* Pb = P + (long)inode * 64;
    const unsigned short* Qb = Q + (long)jnode * 64;
    #pragma unroll
    for (int f = 0; f < 4; ++f) {
      short4v pv = *(const short4v*)&Pb[f * 16 + lq * 4];
      short4v qv = *(const short4v*)&Qb[f * 16 + lq * 4];
      float v0 = silu_f(bf2f((unsigned short)pv[0]) + bf2f((unsigned short)qv[0]) + acc1[f][0]);
      float v1 = silu_f(bf2f((unsigned short)pv[1]) + bf2f((unsigned short)qv[1]) + acc1[f][1]);
      float v2 = silu_f(bf2f((unsigned short)pv[2]) + bf2f((unsigned short)qv[2]) + acc1[f][2]);
      float v3 = silu_f(bf2f((unsigned short)pv[3]) + bf2f((unsigned short)qv[3]) + acc1[f][3]);
      uint2 w;
      w.x = cvt_pk_bf16(v0, v1);
      w.y = cvt_pk_bf16(v2, v3);
      *(uint2*)&Es_w[lr * SE + f * 16 + lq * 4] = w;
    }

    f32x4 acc2[4];
    #pragma unroll
    for (int f = 0; f < 4; ++f) acc2[f] = zero4;
    #pragma unroll
    for (int s = 0; s < 2; ++s) {
      int kb = s * 32 + lq * 8;
      bf16x8 bE = *(const bf16x8*)&Es_w[lr * SE + kb];
      #pragma unroll
      for (int f = 0; f < 4; ++f) {
        bf16x8 aW = *(const bf16x8*)&W2s[(f * 16 + lr) * SW2 + kb];
        acc2[f] = __builtin_amdgcn_mfma_f32_16x16x32_bf16(aW, bE, acc2[f], 0, 0, 0);
      }
    }

    // epilogue: silu+gate -> message tile (ALIASES Es; GEMM2 already consumed)
    #pragma unroll
    for (int f = 0; f < 4; ++f) {
      float o0 = silu_f(acc2[f][0] + bias2[f][0]) * g;
      float o1 = silu_f(acc2[f][1] + bias2[f][1]) * g;
      float o2 = silu_f(acc2[f][2] + bias2[f][2]) * g;
      float o3 = silu_f(acc2[f][3] + bias2[f][3]) * g;
      uint2 w;
      w.x = cvt_pk_bf16(o0, o1);
      w.y = cvt_pk_bf16(o2, o3);
      *(uint2*)&Es_w[lr * SE + f * 16 + lq * 4] = w;
    }

    // segmented sum: hoisted reads + ballot boundary mask (SGPR control)
    float mv[16];
    #pragma unroll
    for (int e = 0; e < 16; ++e) mv[e] = bf2f(Es_w[e * SE + lane]);

    int up = __shfl_up(inode, 1);
    unsigned long long bm = __ballot(inode != up);
    unsigned mask = (unsigned)bm & 0xFFFEu;
    int i0 = __builtin_amdgcn_readlane(inode, 0);
    if (i0 != cur_node) mask |= 1u;

    #pragma unroll
    for (int e = 0; e < 16; ++e) {
      if (mask & (1u << e)) {
        if (use_atomic) atomicAdd(&agg[(long)cur_node * 64 + lane], acc);
        else            agg[(long)cur_node * 64 + lane] = acc;
        use_atomic = false;
        cur_node = __builtin_amdgcn_readlane(inode, e);
        acc = 0.f;
      }
      acc += mv[e];
    }
  }
  atomicAdd(&agg[(long)cur_node * 64 + lane], acc);
}

// ---------------------------------------------------------------------------
// h1_kernel: h1 = silu([Hbf|agg] @ Wn1 + bn1) -> global bf16. Half of Wn1T
// LDS-resident per block (55.3 KB), persistent loop.
// ---------------------------------------------------------------------------
__global__ __launch_bounds__(256, 2) void h1_kernel(
    const unsigned short* __restrict__ Hbf, const float* __restrict__ agg,
    const unsigned short* __restrict__ Wn1T, const float* __restrict__ bn1,
    unsigned short* __restrict__ h1)
{
  __shared__ unsigned short Wl[128 * SN1];   // 55.3 KB

  const int tid  = threadIdx.x;
  const int lane = tid & 63;
  const int wv   = tid >> 6;
  const int lr   = lane & 15;
  const int lq   = lane >> 4;
  const int m0   = wv * 16;
  const int p    = blockIdx.x & 1;           // which 128-col half

  for (int i = tid * 8; i < 128 * SN1; i += 256 * 8)
    *(bf16x8*)&Wl[i] = *(const bf16x8*)&Wn1T[p * 128 * SN1 + i];
  __syncthreads();

  f32x4 zero4 = {0.f, 0.f, 0.f, 0.f};
  for (int t = blockIdx.x >> 1; t < NODE_TILES; t += 256) {
    const int n0 = t * 64;
    int rowa = n0 + m0 + lr;
    int rowc = rowa < N_NODES ? rowa : N_NODES - 1;

    f32x4 acc1[8];
    #pragma unroll
    for (int f = 0; f < 8; ++f) acc1[f] = zero4;
    #pragma unroll
    for (int s = 0; s < 6; ++s) {
      int kb = s * 32 + lq * 8;
      bf16x8 a;
      if (s < 4) {
        a = *(const bf16x8*)&Hbf[(long)rowa * 128 + kb];
      } else {
        const float* pp = agg + (long)rowc * 64 + (kb - 128);
        float4 u = *(const float4*)pp;
        float4 v = *(const float4*)(pp + 4);
        a = pack8(u, v);
      }
      #pragma unroll
      for (int f = 0; f < 8; ++f) {
        bf16x8 b = *(const bf16x8*)&Wl[(f * 16 + lr) * SN1 + kb];
        acc1[f] = __builtin_amdgcn_mfma_f32_16x16x32_bf16(a, b, acc1[f], 0, 0, 0);
      }
    }
    #pragma unroll
    for (int f = 0; f < 8; ++f) {
      int col = p * 128 + f * 16 + lr;
      float bias = bn1[col];
      #pragma unroll
      for (int r = 0; r < 4; ++r) {
        int node = n0 + m0 + lq * 4 + r;
        h1[(long)node * 256 + col] = f2bf(silu_f(acc1[f][r] + bias));
      }
    }
  }
}

// ---------------------------------------------------------------------------
// out_kernel: upd = h1 @ Wn2 + bn2; out = LN(H + upd). Wn2T LDS-resident.
// ---------------------------------------------------------------------------
__global__ __launch_bounds__(256, 2) void out_kernel(
    const float* __restrict__ H, const unsigned short* __restrict__ h1,
    const unsigned short* __restrict__ Wn2T, const float* __restrict__ bn2,
    const float* __restrict__ ln_g, const float* __restrict__ ln_b,
    float* __restrict__ out)
{
  __shared__ unsigned short Wl[128 * SN2];   // 71.7 KB

  const int tid  = threadIdx.x;
  const int lane = tid & 63;
  const int wv   = tid >> 6;
  const int lr   = lane & 15;
  const int lq   = lane >> 4;
  const int m0   = wv * 16;

  for (int i = tid * 8; i < 128 * SN2; i += 256 * 8)
    *(bf16x8*)&Wl[i] = *(const bf16x8*)&Wn2T[i];
  __syncthreads();

  f32x4 zero4 = {0.f, 0.f, 0.f, 0.f};
  for (int t = blockIdx.x; t < NODE_TILES; t += 512) {
    const int n0 = t * 64;
    int rowa = n0 + m0 + lr;

    f32x4 acc2[8];
    #pragma unroll
    for (int f = 0; f < 8; ++f) acc2[f] = zero4;
    #pragma unroll
    for (int s = 0; s < 8; ++s) {
      int kb = s * 32 + lq * 8;
      bf16x8 a = *(const bf16x8*)&h1[(long)rowa * 256 + kb];
      #pragma unroll
      for (int f = 0; f < 8; ++f) {
        bf16x8 b = *(const bf16x8*)&Wl[(f * 16 + lr) * SN2 + kb];
        acc2[f] = __builtin_amdgcn_mfma_f32_16x16x32_bf16(a, b, acc2[f], 0, 0, 0);
      }
    }

    #pragma unroll
    for (int r = 0; r < 4; ++r) {
      int node = n0 + m0 + lq * 4 + r;
      int nc = node < N_NODES ? node : N_NODES - 1;
      float x[8];
      float sum = 0.f, sumsq = 0.f;
      #pragma unroll
      for (int f = 0; f < 8; ++f) {
        int n = f * 16 + lr;
        float u = acc2[f][r] + bn2[n];
        float xv = H[(long)nc * 128 + n] + u;
        x[f] = xv;
        sum += xv;
        sumsq += xv * xv;
      }
      #pragma unroll
      for (int o = 1; o < 16; o <<= 1) {
        sum   += __shfl_xor(sum, o);
        sumsq += __shfl_xor(sumsq, o);
      }
      float mu  = sum * (1.f / 128.f);
      float var = sumsq * (1.f / 128.f) - mu * mu;
      float rstd = rsqrtf(var + 1e-5f);
      if (node < N_NODES) {
        #pragma unroll
        for (int f = 0; f < 8; ++f) {
          int n = f * 16 + lr;
          out[(long)node * 128 + n] = (x[f] - mu) * rstd * ln_g[n] + ln_b[n];
        }
      }
    }
  }
}

extern "C" void kernel_launch(void* const* d_in, const int* in_sizes, int n_in,
                              void* d_out, int out_size, void* d_ws, size_t ws_size,
                              hipStream_t stream) {
  const float* H       = (const float*)d_in[0];
  const float* xyz     = (const float*)d_in[1];
  const int*   eidx    = (const int*)d_in[2];
  const float* estruct = (const float*)d_in[3];
  const float* erest   = (const float*)d_in[4];
  const float* We1     = (const float*)d_in[5];
  const float* be1     = (const float*)d_in[6];
  const float* We2     = (const float*)d_in[7];
  const float* be2     = (const float*)d_in[8];
  const float* Wg1     = (const float*)d_in[9];
  const float* bg1     = (const float*)d_in[10];
  const float* Wg2     = (const float*)d_in[11];
  const float* bg2     = (const float*)d_in[12];
  const float* Wn1     = (const float*)d_in[13];
  const float* bn1     = (const float*)d_in[14];
  const float* Wn2     = (const float*)d_in[15];
  const float* bn2     = (const float*)d_in[16];
  const float* ln_g    = (const float*)d_in[17];
  const float* ln_b    = (const float*)d_in[18];

  char* ws = (char*)d_ws;
  float*          agg    = (float*)(ws + 0);                    //  12,812,288 (50048*64*4)
  unsigned short* Hbf    = (unsigned short*)(ws + 12812288);    //  12,812,288 (50048*128*2)
  unsigned short* rec    = (unsigned short*)(ws + 25624576);    //  25,600,000 (800000*32, slot-indexed)
  unsigned short* P      = (unsigned short*)(ws + 51224576);    //   6,400,000
  unsigned short* Qm     = (unsigned short*)(ws + 57624576);    //   6,400,000
  int*            cnt    = (int*)(ws + 64024576);               //     200,192
  int*            rowptr = (int*)(ws + 64224768);               //     200,192 (scan temp)
  int*            cursor = (int*)(ws + 64424960);               //     200,192
  unsigned short* WpqT   = (unsigned short*)(ws + 64625152);    //      34,816
  unsigned short* We2T   = (unsigned short*)(ws + 64659968);    //       9,216
  unsigned short* Wn1T   = (unsigned short*)(ws + 64669184);    //     110,592 (256*216)
  unsigned short* Wn2T   = (unsigned short*)(ws + 64779776);    //      71,680 (128*280)
  unsigned short* WrT    = (unsigned short*)(ws + 64851456);    //       4,096
  int*            bsum   = (int*)(ws + 64855552);               //         512
  int*            boff   = (int*)(ws + 64856064);               //         512
  unsigned short* h1     = (unsigned short*)(ws + 64856576);    //  25,624,576 (50048*256*2)
  float* out = (float*)d_out;

  hipMemsetAsync(cnt, 0, (size_t)N_NODES * sizeof(int), stream);

  hipLaunchKernelGGL(prep_hist, dim3(3125), dim3(256), 0, stream,
                     eidx, We1, be1, We2, Wn1, Wn2, WpqT, We2T, Wn1T, Wn2T, WrT, cnt);
  hipLaunchKernelGGL(scan_local, dim3(SCAN_B), dim3(512), 0, stream,
                     cnt, rowptr, bsum);
  hipLaunchKernelGGL(scan_mid, dim3(1), dim3(128), 0, stream,
                     bsum, boff);
  hipLaunchKernelGGL(scan_add, dim3(SCAN_B), dim3(512), 0, stream,
                     rowptr, boff, cursor, (float4*)agg);
  hipLaunchKernelGGL(fill_reorder, dim3(3125), dim3(256), 0, stream,
                     eidx, xyz, estruct, erest, cursor,
                     Wg1, bg1, Wg2, bg2, rec);
  hipLaunchKernelGGL(pq_kernel, dim3(NODE_TILES), dim3(256), 0, stream,
                     H, WpqT, P, Qm, Hbf);
  hipLaunchKernelGGL(edge_compute, dim3(EC_GRID), dim3(256), 0, stream,
                     P, Qm, rec, We2T, be2, WrT, agg);
  hipLaunchKernelGGL(h1_kernel, dim3(512), dim3(256), 0, stream,
                     Hbf, agg, Wn1T, bn1, h1);
  hipLaunchKernelGGL(out_kernel, dim3(512), dim3(256), 0, stream,
                     H, h1, Wn2T, bn2, ln_g, ln_b, out);
}

// Round 12
// 373.049 us; speedup vs baseline: 1.0326x; 1.0326x over previous
//
#include <hip/hip_runtime.h>
#include <stdint.h>

#define N_NODES 50000
#define N_EDGES 800000
#define NODE_TILES 782              // ceil(50000/64)

#define SE   72    // e-tile stride (bf16); message tile ALIASES this buffer
#define SW2  72
#define SPQ  136   // pq kernel strides (K=128)
#define SN1  216   // Wn1T row stride (K=192) -- dword 108 == 12 mod 32: 2-way
#define SN2  280   // Wn2T row stride (K=256) -- dword 140 == 12 mod 32: 2-way
#define ATS  40    // edge A-tile row stride (dword 20: 2-way, 16B-aligned)

#define EC_GRID 1563  // 1563*4 waves * 8 tiles = 50016 >= 50000 (6 blk/CU capacity)
#define EC_CHUNK 8

#define SCAN_B 98     // 98*512 = 50176 >= 50000

typedef short bf16x8 __attribute__((ext_vector_type(8)));
typedef short short4v __attribute__((ext_vector_type(4)));
typedef unsigned short ushort8 __attribute__((ext_vector_type(8)));
typedef unsigned int uint4v __attribute__((ext_vector_type(4)));
typedef float f32x4  __attribute__((ext_vector_type(4)));

static __device__ __forceinline__ unsigned short f2bf(float f) {
  unsigned int x = __float_as_uint(f);
  unsigned int r = (x + 0x7fffu + ((x >> 16) & 1u)) >> 16;
  return (unsigned short)r;
}
static __device__ __forceinline__ float bf2f(unsigned short u) {
  return __uint_as_float(((unsigned int)u) << 16);
}
static __device__ __forceinline__ float silu_f(float x) {
  return x * __builtin_amdgcn_rcpf(1.0f + __expf(-x));
}
static __device__ __forceinline__ float sigmoid_f(float x) {
  return __builtin_amdgcn_rcpf(1.0f + __expf(-x));
}
static __device__ __forceinline__ unsigned int cvt_pk_bf16(float lo, float hi) {
  unsigned int r;
  asm("v_cvt_pk_bf16_f32 %0, %1, %2" : "=v"(r) : "v"(lo), "v"(hi));
  return r;
}
static __device__ __forceinline__ bf16x8 pack8(float4 u, float4 v) {
  bf16x8 w;
  w[0] = (short)f2bf(u.x); w[1] = (short)f2bf(u.y);
  w[2] = (short)f2bf(u.z); w[3] = (short)f2bf(u.w);
  w[4] = (short)f2bf(v.x); w[5] = (short)f2bf(v.y);
  w[6] = (short)f2bf(v.z); w[7] = (short)f2bf(v.w);
  return w;
}

// ---------------------------------------------------------------------------
// prep: natural transposed bf16 weights + destination histogram.
// ---------------------------------------------------------------------------
__global__ void prep_hist(
    const int* __restrict__ eidx,
    const float* __restrict__ We1, const float* __restrict__ be1,
    const float* __restrict__ We2,
    const float* __restrict__ Wn1, const float* __restrict__ Wn2,
    unsigned short* __restrict__ WpqT, unsigned short* __restrict__ We2T,
    unsigned short* __restrict__ Wn1T, unsigned short* __restrict__ Wn2T,
    unsigned short* __restrict__ WrT,
    int* __restrict__ cnt)
{
  const int gid = blockIdx.x * 256 + threadIdx.x;
  const int gsz = gridDim.x * 256;
  for (int i = gid; i < 128 * SPQ; i += gsz) {
    int n = i / SPQ, k = i % SPQ;
    unsigned short v = 0;
    if (k < 128) v = (n < 64) ? f2bf(We1[k * 64 + n]) : f2bf(We1[(128 + k) * 64 + (n - 64)]);
    WpqT[i] = v;
  }
  for (int i = gid; i < 64 * SW2; i += gsz) {
    int n = i / SW2, k = i % SW2;
    We2T[i] = (k < 64) ? f2bf(We2[k * 64 + n]) : (unsigned short)0;
  }
  for (int i = gid; i < 256 * SN1; i += gsz) {
    int n = i / SN1, k = i % SN1;
    Wn1T[i] = (k < 192) ? f2bf(Wn1[k * 256 + n]) : (unsigned short)0;
  }
  for (int i = gid; i < 128 * SN2; i += gsz) {
    int n = i / SN2, k = i % SN2;
    Wn2T[i] = (k < 256) ? f2bf(Wn2[k * 128 + n]) : (unsigned short)0;
  }
  for (int i = gid; i < 64 * 32; i += gsz) {
    int n = i >> 5, k = i & 31;
    float v = 0.f;
    if (k < 2)       v = We1[256 * 64 + n];
    else if (k < 4)  v = We1[257 * 64 + n];
    else if (k < 12) v = We1[(258 + (k - 4)) * 64 + n];
    else if (k == 12) v = be1[n];
    else if (k == 13) { float w = We1[256 * 64 + n]; v = w - bf2f(f2bf(w)); }
    else if (k == 14) { float w = We1[257 * 64 + n]; v = w - bf2f(f2bf(w)); }
    else if (k == 15) { float w = be1[n];            v = w - bf2f(f2bf(w)); }
    WrT[i] = (k < 16) ? f2bf(v) : (unsigned short)0;
  }
  if (gid < N_EDGES) atomicAdd(&cnt[eidx[gid]], 1);
}

// ---------------------------------------------------------------------------
// hierarchical scan (coalesced, no per-thread arrays)
// ---------------------------------------------------------------------------
__global__ __launch_bounds__(512) void scan_local(
    const int* __restrict__ cnt, int* __restrict__ rowptr,
    int* __restrict__ bsum)
{
  __shared__ int wsum[8], woff[8];
  const int t = threadIdx.x;
  const int idx = blockIdx.x * 512 + t;
  const int lane = t & 63, wid = t >> 6;
  int c = (idx < N_NODES) ? cnt[idx] : 0;
  int v = c;
  #pragma unroll
  for (int o = 1; o < 64; o <<= 1) {
    int u = __shfl_up(v, o);
    if (lane >= o) v += u;
  }
  if (lane == 63) wsum[wid] = v;
  __syncthreads();
  if (t == 0) {
    int a = 0;
    #pragma unroll
    for (int w = 0; w < 8; ++w) { woff[w] = a; a += wsum[w]; }
    bsum[blockIdx.x] = a;
  }
  __syncthreads();
  if (idx < N_NODES) rowptr[idx] = woff[wid] + (v - c);
}

__global__ __launch_bounds__(128) void scan_mid(
    const int* __restrict__ bsum, int* __restrict__ boff)
{
  __shared__ int ws[2];
  const int t = threadIdx.x;
  const int lane = t & 63, wid = t >> 6;
  int c = (t < SCAN_B) ? bsum[t] : 0;
  int v = c;
  #pragma unroll
  for (int o = 1; o < 64; o <<= 1) {
    int u = __shfl_up(v, o);
    if (lane >= o) v += u;
  }
  if (lane == 63) ws[wid] = v;
  __syncthreads();
  int add = (wid == 1) ? ws[0] : 0;
  if (t < SCAN_B) boff[t] = add + (v - c);
}

// scan_add also zeroes agg (folds the 12.8 MB memset dispatch away)
__global__ __launch_bounds__(512) void scan_add(
    const int* __restrict__ rowptr, const int* __restrict__ boff,
    int* __restrict__ cursor, float4* __restrict__ agg)
{
  const int idx = blockIdx.x * 512 + threadIdx.x;
  if (idx < N_NODES) cursor[idx] = rowptr[idx] + boff[blockIdx.x];
  if (idx < 50048) {
    float4 z = make_float4(0.f, 0.f, 0.f, 0.f);
    float4* p = agg + (long)idx * 16;
    #pragma unroll
    for (int k = 0; k < 16; ++k) p[k] = z;
  }
}

// ---------------------------------------------------------------------------
// fill_reorder (R17: nt stores REVERTED -- they evicted rec from L2 and cost
// edge_compute +8.6 MB FETCH / +20 us in R11). Plain 16-B stores keep rec
// L2-warm for the consumer. One thread per edge, gate MLP, 32-B record
// scattered to rec[pos].
// Record: [0:8) d2h,d2l,dlh,dll  [8:24) struct bf16  [24:28) g  [28:32) i|j<<16
// ---------------------------------------------------------------------------
__global__ void fill_reorder(
    const int* __restrict__ eidx, const float* __restrict__ xyz,
    const float* __restrict__ estruct, const float* __restrict__ erest,
    int* __restrict__ cursor,
    const float* __restrict__ Wg1, const float* __restrict__ bg1,
    const float* __restrict__ Wg2, const float* __restrict__ bg2,
    unsigned short* __restrict__ rec)
{
  int e = blockIdx.x * 256 + threadIdx.x;
  if (e >= N_EDGES) return;
  int i = eidx[e], j = eidx[N_EDGES + e];
  float dx = xyz[i * 3 + 0] - xyz[j * 3 + 0];
  float dy = xyz[i * 3 + 1] - xyz[j * 3 + 1];
  float dz = xyz[i * 3 + 2] - xyz[j * 3 + 2];
  float d2 = dx * dx + dy * dy + dz * dz;
  float dist = sqrtf(d2 + 1e-9f);
  float rest = erest[e];
  float dl = (dist - rest) / (rest + 1e-9f);
  float4 s0 = *(const float4*)&estruct[e * 8];
  float4 s1 = *(const float4*)&estruct[e * 8 + 4];
  float st[8] = {s0.x, s0.y, s0.z, s0.w, s1.x, s1.y, s1.z, s1.w};
  float gsum = 0.f;
  #pragma unroll
  for (int h = 0; h < 32; ++h) {
    float a = bg1[h] + d2 * Wg1[0 * 32 + h] + dl * Wg1[1 * 32 + h];
    #pragma unroll
    for (int c = 0; c < 8; ++c) a += st[c] * Wg1[(2 + c) * 32 + h];
    gsum += silu_f(a) * Wg2[h];
  }
  float g = sigmoid_f(gsum + bg2[0]);

  unsigned short d2h = f2bf(d2);
  unsigned short d2l = f2bf(d2 - bf2f(d2h));
  unsigned short dlh = f2bf(dl);
  unsigned short dll = f2bf(dl - bf2f(dlh));

  ushort8 w0;
  w0[0] = d2h; w0[1] = d2l; w0[2] = dlh; w0[3] = dll;
  w0[4] = f2bf(st[0]); w0[5] = f2bf(st[1]); w0[6] = f2bf(st[2]); w0[7] = f2bf(st[3]);
  uint4v w1;
  w1[0] = (unsigned int)f2bf(st[4]) | ((unsigned int)f2bf(st[5]) << 16);
  w1[1] = (unsigned int)f2bf(st[6]) | ((unsigned int)f2bf(st[7]) << 16);
  w1[2] = __float_as_uint(g);
  w1[3] = (unsigned int)i | ((unsigned int)j << 16);

  int pos = atomicAdd(&cursor[i], 1);
  unsigned short* dst = rec + (long)pos * 16;
  *(uint4v*)dst = *(uint4v*)&w0;
  *(uint4v*)(dst + 8) = w1;
}

// ---------------------------------------------------------------------------
// pq: standalone, LDS-free A-path. Stage only Ws (34.8 KB) + one barrier;
// each of 4 waves computes 16 rows, loading H fragments directly
// (f32 -> pack8 -> Hbf export inline). Grid = NODE_TILES.
// ---------------------------------------------------------------------------
__global__ __launch_bounds__(256, 4) void pq_kernel(
    const float* __restrict__ H, const unsigned short* __restrict__ WpqT,
    unsigned short* __restrict__ P, unsigned short* __restrict__ Q,
    unsigned short* __restrict__ Hbf)
{
  __shared__ unsigned short Ws[128 * SPQ];   // 34.8 KB (only LDS)

  const int tid  = threadIdx.x;
  const int lane = tid & 63;
  const int wv   = tid >> 6;
  const int lr   = lane & 15;
  const int lq   = lane >> 4;
  const int n0   = blockIdx.x * 64;
  const int m0   = wv * 16;

  for (int i = tid * 8; i < 128 * SPQ; i += 256 * 8)
    *(bf16x8*)&Ws[i] = *(const bf16x8*)&WpqT[i];
  __syncthreads();

  const int rowa = n0 + m0 + lr;
  const int rowc = rowa < N_NODES ? rowa : N_NODES - 1;

  f32x4 zero4 = {0.f, 0.f, 0.f, 0.f};
  f32x4 acc[8];
  #pragma unroll
  for (int f = 0; f < 8; ++f) acc[f] = zero4;

  #pragma unroll
  for (int s = 0; s < 4; ++s) {
    int kb = s * 32 + lq * 8;
    const float* p = H + (long)rowc * 128 + kb;
    float4 u = *(const float4*)p;
    float4 v = *(const float4*)(p + 4);
    bf16x8 a = pack8(u, v);
    *(bf16x8*)&Hbf[(long)rowa * 128 + kb] = a;   // export (each (row,kb) once)
    #pragma unroll
    for (int f = 0; f < 8; ++f) {
      bf16x8 b = *(const bf16x8*)&Ws[(f * 16 + lr) * SPQ + kb];
      acc[f] = __builtin_amdgcn_mfma_f32_16x16x32_bf16(a, b, acc[f], 0, 0, 0);
    }
  }
  #pragma unroll
  for (int f = 0; f < 8; ++f) {
    #pragma unroll
    for (int r = 0; r < 4; ++r) {
      int node = n0 + m0 + lq * 4 + r;
      if (node < N_NODES) {
        if (f < 4) P[(long)node * 64 + f * 16 + lr] = f2bf(acc[f][r]);
        else       Q[(long)node * 64 + (f - 4) * 16 + lr] = f2bf(acc[f][r]);
      }
    }
  }
}

// ---------------------------------------------------------------------------
// edge_compute: 6 blk/CU (Es/message aliasing, 23.5 KB LDS), chunk 8.
// Sequential slot-indexed rec reads (L2-warm now that nt is gone);
// ballot-based segmented sum.
// ---------------------------------------------------------------------------
__global__ __launch_bounds__(256, 6) void edge_compute(
    const unsigned short* __restrict__ P, const unsigned short* __restrict__ Q,
    const unsigned short* __restrict__ rec,
    const unsigned short* __restrict__ We2T, const float* __restrict__ be2,
    const unsigned short* __restrict__ WrT,
    float* __restrict__ agg)
{
  __shared__ unsigned short W2s[64 * SW2];       // 9.2 KB
  __shared__ unsigned short Es [4 * 16 * SE];    // 9.2 KB (also message tile)
  __shared__ unsigned short At [4 * 16 * ATS];   // 5.1 KB  (23.5 KB total)

  const int tid  = threadIdx.x;
  const int lane = tid & 63;
  const int wv   = tid >> 6;
  const int lr   = lane & 15;
  const int lq   = lane >> 4;

  for (int i = tid * 8; i < 64 * SW2; i += 256 * 8)
    *(bf16x8*)&W2s[i] = *(const bf16x8*)&We2T[i];

  unsigned short* Es_w = &Es[wv * 16 * SE];
  unsigned short* At_w = &At[wv * 16 * ATS];

  if (lane < 16) {
    ushort8 z;
    #pragma unroll
    for (int c = 0; c < 8; ++c) z[c] = 0;
    *(ushort8*)&At_w[lane * ATS + 16] = z;
    *(ushort8*)&At_w[lane * ATS + 24] = z;
  }

  bf16x8 aWr[4];
  float bias2[4][4];
  #pragma unroll
  for (int f = 0; f < 4; ++f) {
    aWr[f] = *(const bf16x8*)&WrT[(f * 16 + lr) * 32 + lq * 8];
    #pragma unroll
    for (int r = 0; r < 4; ++r) bias2[f][r] = be2[f * 16 + lq * 4 + r];
  }
  __syncthreads();

  const int n_tiles = N_EDGES / 16;  // 50000
  const int wid = blockIdx.x * 4 + wv;
  const int t0 = wid * EC_CHUNK;
  const int t1 = (t0 + EC_CHUNK < n_tiles) ? (t0 + EC_CHUNK) : n_tiles;
  if (t0 >= n_tiles) return;

  f32x4 zero4 = {0.f, 0.f, 0.f, 0.f};
  int   cur_node;
  {
    int ij0 = *(const int*)(rec + (long)t0 * 16 * 16 + 14);
    cur_node = ij0 & 0xffff;
  }
  float acc        = 0.f;
  bool  use_atomic = true;

  for (int tile = t0; tile < t1; ++tile) {
    const int s0 = tile * 16;

    const unsigned short* rp = rec + (long)(s0 + lr) * 16;
    ushort8 ra = *(const ushort8*)rp;          // d2h,d2l,dlh,dll,st0..3
    uint4   rb = *(const uint4*)(rp + 8);      // st4..7 | g | i,j
    float g     = __uint_as_float(rb.z);
    int   inode = (int)(rb.w & 0xffff);
    int   jnode = (int)((rb.w >> 16) & 0xffff);

    if (lane < 16) {
      ushort8 w1;
      w1[0] = (unsigned short)(rb.x & 0xffff);
      w1[1] = (unsigned short)(rb.x >> 16);
      w1[2] = (unsigned short)(rb.y & 0xffff);
      w1[3] = (unsigned short)(rb.y >> 16);
      w1[4] = 0x3F80u; w1[5] = (unsigned short)ra[0];
      w1[6] = (unsigned short)ra[2]; w1[7] = 0x3F80u;
      *(ushort8*)&At_w[lane * ATS]     = ra;
      *(ushort8*)&At_w[lane * ATS + 8] = w1;
    }

    bf16x8 bA = *(const bf16x8*)&At_w[lr * ATS + lq * 8];
    f32x4 acc1[4];
    #pragma unroll
    for (int f = 0; f < 4; ++f)
      acc1[f] = __builtin_amdgcn_mfma_f32_16x16x32_bf16(aWr[f], bA, zero4, 0, 0, 0);

    const unsigned short* Pb = P + (long)inode * 64;
    const unsigned short* Qb = Q + (long)jnode * 64;
    #pragma unroll
    for (int f = 0; f < 4; ++f) {
      short4v pv = *(const short4v*)&Pb[f * 16 + lq * 4];
      short4v qv = *(const short4v*)&Qb[f * 16 + lq * 4];
      float v0 = silu_f(bf2f((unsigned short)pv[0]) + bf2f((unsigned short)qv[0]) + acc1[f][0]);
      float v1 = silu_f(bf2f((unsigned short)pv[1]) + bf2f((unsigned short)qv[1]) + acc1[f][1]);
      float v2 = silu_f(bf2f((unsigned short)pv[2]) + bf2f((unsigned short)qv[2]) + acc1[f][2]);
      float v3 = silu_f(bf2f((unsigned short)pv[3]) + bf2f((unsigned short)qv[3]) + acc1[f][3]);
      uint2 w;
      w.x = cvt_pk_bf16(v0, v1);
      w.y = cvt_pk_bf16(v2, v3);
      *(uint2*)&Es_w[lr * SE + f * 16 + lq * 4] = w;
    }

    f32x4 acc2[4];
    #pragma unroll
    for (int f = 0; f < 4; ++f) acc2[f] = zero4;
    #pragma unroll
    for (int s = 0; s < 2; ++s) {
      int kb = s * 32 + lq * 8;
      bf16x8 bE = *(const bf16x8*)&Es_w[lr * SE + kb];
      #pragma unroll
      for (int f = 0; f < 4; ++f) {
        bf16x8 aW = *(const bf16x8*)&W2s[(f * 16 + lr) * SW2 + kb];
        acc2[f] = __builtin_amdgcn_mfma_f32_16x16x32_bf16(aW, bE, acc2[f], 0, 0, 0);
      }
    }

    // epilogue: silu+gate -> message tile (ALIASES Es; GEMM2 already consumed)
    #pragma unroll
    for (int f = 0; f < 4; ++f) {
      float o0 = silu_f(acc2[f][0] + bias2[f][0]) * g;
      float o1 = silu_f(acc2[f][1] + bias2[f][1]) * g;
      float o2 = silu_f(acc2[f][2] + bias2[f][2]) * g;
      float o3 = silu_f(acc2[f][3] + bias2[f][3]) * g;
      uint2 w;
      w.x = cvt_pk_bf16(o0, o1);
      w.y = cvt_pk_bf16(o2, o3);
      *(uint2*)&Es_w[lr * SE + f * 16 + lq * 4] = w;
    }

    // segmented sum: hoisted reads + ballot boundary mask (SGPR control)
    float mv[16];
    #pragma unroll
    for (int e = 0; e < 16; ++e) mv[e] = bf2f(Es_w[e * SE + lane]);

    int up = __shfl_up(inode, 1);
    unsigned long long bm = __ballot(inode != up);
    unsigned mask = (unsigned)bm & 0xFFFEu;
    int i0 = __builtin_amdgcn_readlane(inode, 0);
    if (i0 != cur_node) mask |= 1u;

    #pragma unroll
    for (int e = 0; e < 16; ++e) {
      if (mask & (1u << e)) {
        if (use_atomic) atomicAdd(&agg[(long)cur_node * 64 + lane], acc);
        else            agg[(long)cur_node * 64 + lane] = acc;
        use_atomic = false;
        cur_node = __builtin_amdgcn_readlane(inode, e);
        acc = 0.f;
      }
      acc += mv[e];
    }
  }
  atomicAdd(&agg[(long)cur_node * 64 + lane], acc);
}

// ---------------------------------------------------------------------------
// h1_kernel: h1 = silu([Hbf|agg] @ Wn1 + bn1) -> global bf16. Half of Wn1T
// LDS-resident per block (55.3 KB), persistent loop.
// ---------------------------------------------------------------------------
__global__ __launch_bounds__(256, 2) void h1_kernel(
    const unsigned short* __restrict__ Hbf, const float* __restrict__ agg,
    const unsigned short* __restrict__ Wn1T, const float* __restrict__ bn1,
    unsigned short* __restrict__ h1)
{
  __shared__ unsigned short Wl[128 * SN1];   // 55.3 KB

  const int tid  = threadIdx.x;
  const int lane = tid & 63;
  const int wv   = tid >> 6;
  const int lr   = lane & 15;
  const int lq   = lane >> 4;
  const int m0   = wv * 16;
  const int p    = blockIdx.x & 1;           // which 128-col half

  for (int i = tid * 8; i < 128 * SN1; i += 256 * 8)
    *(bf16x8*)&Wl[i] = *(const bf16x8*)&Wn1T[p * 128 * SN1 + i];
  __syncthreads();

  f32x4 zero4 = {0.f, 0.f, 0.f, 0.f};
  for (int t = blockIdx.x >> 1; t < NODE_TILES; t += 256) {
    const int n0 = t * 64;
    int rowa = n0 + m0 + lr;
    int rowc = rowa < N_NODES ? rowa : N_NODES - 1;

    f32x4 acc1[8];
    #pragma unroll
    for (int f = 0; f < 8; ++f) acc1[f] = zero4;
    #pragma unroll
    for (int s = 0; s < 6; ++s) {
      int kb = s * 32 + lq * 8;
      bf16x8 a;
      if (s < 4) {
        a = *(const bf16x8*)&Hbf[(long)rowa * 128 + kb];
      } else {
        const float* pp = agg + (long)rowc * 64 + (kb - 128);
        float4 u = *(const float4*)pp;
        float4 v = *(const float4*)(pp + 4);
        a = pack8(u, v);
      }
      #pragma unroll
      for (int f = 0; f < 8; ++f) {
        bf16x8 b = *(const bf16x8*)&Wl[(f * 16 + lr) * SN1 + kb];
        acc1[f] = __builtin_amdgcn_mfma_f32_16x16x32_bf16(a, b, acc1[f], 0, 0, 0);
      }
    }
    #pragma unroll
    for (int f = 0; f < 8; ++f) {
      int col = p * 128 + f * 16 + lr;
      float bias = bn1[col];
      #pragma unroll
      for (int r = 0; r < 4; ++r) {
        int node = n0 + m0 + lq * 4 + r;
        h1[(long)node * 256 + col] = f2bf(silu_f(acc1[f][r] + bias));
      }
    }
  }
}

// ---------------------------------------------------------------------------
// out_kernel: upd = h1 @ Wn2 + bn2; out = LN(H + upd). Wn2T LDS-resident.
// ---------------------------------------------------------------------------
__global__ __launch_bounds__(256, 2) void out_kernel(
    const float* __restrict__ H, const unsigned short* __restrict__ h1,
    const unsigned short* __restrict__ Wn2T, const float* __restrict__ bn2,
    const float* __restrict__ ln_g, const float* __restrict__ ln_b,
    float* __restrict__ out)
{
  __shared__ unsigned short Wl[128 * SN2];   // 71.7 KB

  const int tid  = threadIdx.x;
  const int lane = tid & 63;
  const int wv   = tid >> 6;
  const int lr   = lane & 15;
  const int lq   = lane >> 4;
  const int m0   = wv * 16;

  for (int i = tid * 8; i < 128 * SN2; i += 256 * 8)
    *(bf16x8*)&Wl[i] = *(const bf16x8*)&Wn2T[i];
  __syncthreads();

  f32x4 zero4 = {0.f, 0.f, 0.f, 0.f};
  for (int t = blockIdx.x; t < NODE_TILES; t += 512) {
    const int n0 = t * 64;
    int rowa = n0 + m0 + lr;

    f32x4 acc2[8];
    #pragma unroll
    for (int f = 0; f < 8; ++f) acc2[f] = zero4;
    #pragma unroll
    for (int s = 0; s < 8; ++s) {
      int kb = s * 32 + lq * 8;
      bf16x8 a = *(const bf16x8*)&h1[(long)rowa * 256 + kb];
      #pragma unroll
      for (int f = 0; f < 8; ++f) {
        bf16x8 b = *(const bf16x8*)&Wl[(f * 16 + lr) * SN2 + kb];
        acc2[f] = __builtin_amdgcn_mfma_f32_16x16x32_bf16(a, b, acc2[f], 0, 0, 0);
      }
    }

    #pragma unroll
    for (int r = 0; r < 4; ++r) {
      int node = n0 + m0 + lq * 4 + r;
      int nc = node < N_NODES ? node : N_NODES - 1;
      float x[8];
      float sum = 0.f, sumsq = 0.f;
      #pragma unroll
      for (int f = 0; f < 8; ++f) {
        int n = f * 16 + lr;
        float u = acc2[f][r] + bn2[n];
        float xv = H[(long)nc * 128 + n] + u;
        x[f] = xv;
        sum += xv;
        sumsq += xv * xv;
      }
      #pragma unroll
      for (int o = 1; o < 16; o <<= 1) {
        sum   += __shfl_xor(sum, o);
        sumsq += __shfl_xor(sumsq, o);
      }
      float mu  = sum * (1.f / 128.f);
      float var = sumsq * (1.f / 128.f) - mu * mu;
      float rstd = rsqrtf(var + 1e-5f);
      if (node < N_NODES) {
        #pragma unroll
        for (int f = 0; f < 8; ++f) {
          int n = f * 16 + lr;
          out[(long)node * 128 + n] = (x[f] - mu) * rstd * ln_g[n] + ln_b[n];
        }
      }
    }
  }
}

extern "C" void kernel_launch(void* const* d_in, const int* in_sizes, int n_in,
                              void* d_out, int out_size, void* d_ws, size_t ws_size,
                              hipStream_t stream) {
  const float* H       = (const float*)d_in[0];
  const float* xyz     = (const float*)d_in[1];
  const int*   eidx    = (const int*)d_in[2];
  const float* estruct = (const float*)d_in[3];
  const float* erest   = (const float*)d_in[4];
  const float* We1     = (const float*)d_in[5];
  const float* be1     = (const float*)d_in[6];
  const float* We2     = (const float*)d_in[7];
  const float* be2     = (const float*)d_in[8];
  const float* Wg1     = (const float*)d_in[9];
  const float* bg1     = (const float*)d_in[10];
  const float* Wg2     = (const float*)d_in[11];
  const float* bg2     = (const float*)d_in[12];
  const float* Wn1     = (const float*)d_in[13];
  const float* bn1     = (const float*)d_in[14];
  const float* Wn2     = (const float*)d_in[15];
  const float* bn2     = (const float*)d_in[16];
  const float* ln_g    = (const float*)d_in[17];
  const float* ln_b    = (const float*)d_in[18];

  char* ws = (char*)d_ws;
  float*          agg    = (float*)(ws + 0);                    //  12,812,288 (50048*64*4)
  unsigned short* Hbf    = (unsigned short*)(ws + 12812288);    //  12,812,288 (50048*128*2)
  unsigned short* rec    = (unsigned short*)(ws + 25624576);    //  25,600,000 (800000*32, slot-indexed)
  unsigned short* P      = (unsigned short*)(ws + 51224576);    //   6,400,000
  unsigned short* Qm     = (unsigned short*)(ws + 57624576);    //   6,400,000
  int*            cnt    = (int*)(ws + 64024576);               //     200,192
  int*            rowptr = (int*)(ws + 64224768);               //     200,192 (scan temp)
  int*            cursor = (int*)(ws + 64424960);               //     200,192
  unsigned short* WpqT   = (unsigned short*)(ws + 64625152);    //      34,816
  unsigned short* We2T   = (unsigned short*)(ws + 64659968);    //       9,216
  unsigned short* Wn1T   = (unsigned short*)(ws + 64669184);    //     110,592 (256*216)
  unsigned short* Wn2T   = (unsigned short*)(ws + 64779776);    //      71,680 (128*280)
  unsigned short* WrT    = (unsigned short*)(ws + 64851456);    //       4,096
  int*            bsum   = (int*)(ws + 64855552);               //         512
  int*            boff   = (int*)(ws + 64856064);               //         512
  unsigned short* h1     = (unsigned short*)(ws + 64856576);    //  25,624,576 (50048*256*2)
  float* out = (float*)d_out;

  hipMemsetAsync(cnt, 0, (size_t)N_NODES * sizeof(int), stream);

  hipLaunchKernelGGL(prep_hist, dim3(3125), dim3(256), 0, stream,
                     eidx, We1, be1, We2, Wn1, Wn2, WpqT, We2T, Wn1T, Wn2T, WrT, cnt);
  hipLaunchKernelGGL(scan_local, dim3(SCAN_B), dim3(512), 0, stream,
                     cnt, rowptr, bsum);
  hipLaunchKernelGGL(scan_mid, dim3(1), dim3(128), 0, stream,
                     bsum, boff);
  hipLaunchKernelGGL(scan_add, dim3(SCAN_B), dim3(512), 0, stream,
                     rowptr, boff, cursor, (float4*)agg);
  hipLaunchKernelGGL(fill_reorder, dim3(3125), dim3(256), 0, stream,
                     eidx, xyz, estruct, erest, cursor,
                     Wg1, bg1, Wg2, bg2, rec);
  hipLaunchKernelGGL(pq_kernel, dim3(NODE_TILES), dim3(256), 0, stream,
                     H, WpqT, P, Qm, Hbf);
  hipLaunchKernelGGL(edge_compute, dim3(EC_GRID), dim3(256), 0, stream,
                     P, Qm, rec, We2T, be2, WrT, agg);
  hipLaunchKernelGGL(h1_kernel, dim3(512), dim3(256), 0, stream,
                     Hbf, agg, Wn1T, bn1, h1);
  hipLaunchKernelGGL(out_kernel, dim3(512), dim3(256), 0, stream,
                     H, h1, Wn2T, bn2, ln_g, ln_b, out);
}

// Round 13
// 362.288 us; speedup vs baseline: 1.0633x; 1.0297x over previous
//
#include <hip/hip_runtime.h>
#include <stdint.h>

#define N_NODES 50000
#define N_EDGES 800000
#define NODE_TILES 782              // ceil(50000/64)

#define SE   72    // e-tile stride (bf16); message tile ALIASES this buffer
#define SW2  72
#define SPQ  136   // pq kernel strides (K=128)
#define SN1  216   // Wn1T row stride (K=192) -- dword 108 == 12 mod 32: 2-way
#define SN2  280   // Wn2T row stride (K=256) -- dword 140 == 12 mod 32: 2-way
#define ATS  40    // edge A-tile row stride (dword 20: 2-way, 16B-aligned)

#define EC_GRID 962   // R8-measured best: 962*4 waves * 13 tiles = 50024 >= 50000
#define EC_CHUNK 13   // grid itself caps ~3.8 blk/CU; fewer blocks = less weight
                      // re-staging traffic (R12: 1563 blocks cost +8.3 MB FETCH)

#define SCAN_B 98     // 98*512 = 50176 >= 50000

typedef short bf16x8 __attribute__((ext_vector_type(8)));
typedef short short4v __attribute__((ext_vector_type(4)));
typedef unsigned short ushort8 __attribute__((ext_vector_type(8)));
typedef unsigned int uint4v __attribute__((ext_vector_type(4)));
typedef float f32x4  __attribute__((ext_vector_type(4)));

static __device__ __forceinline__ unsigned short f2bf(float f) {
  unsigned int x = __float_as_uint(f);
  unsigned int r = (x + 0x7fffu + ((x >> 16) & 1u)) >> 16;
  return (unsigned short)r;
}
static __device__ __forceinline__ float bf2f(unsigned short u) {
  return __uint_as_float(((unsigned int)u) << 16);
}
static __device__ __forceinline__ float silu_f(float x) {
  return x * __builtin_amdgcn_rcpf(1.0f + __expf(-x));
}
static __device__ __forceinline__ float sigmoid_f(float x) {
  return __builtin_amdgcn_rcpf(1.0f + __expf(-x));
}
static __device__ __forceinline__ unsigned int cvt_pk_bf16(float lo, float hi) {
  unsigned int r;
  asm("v_cvt_pk_bf16_f32 %0, %1, %2" : "=v"(r) : "v"(lo), "v"(hi));
  return r;
}
static __device__ __forceinline__ bf16x8 pack8(float4 u, float4 v) {
  bf16x8 w;
  w[0] = (short)f2bf(u.x); w[1] = (short)f2bf(u.y);
  w[2] = (short)f2bf(u.z); w[3] = (short)f2bf(u.w);
  w[4] = (short)f2bf(v.x); w[5] = (short)f2bf(v.y);
  w[6] = (short)f2bf(v.z); w[7] = (short)f2bf(v.w);
  return w;
}

// ---------------------------------------------------------------------------
// prep: natural transposed bf16 weights + destination histogram.
// ---------------------------------------------------------------------------
__global__ void prep_hist(
    const int* __restrict__ eidx,
    const float* __restrict__ We1, const float* __restrict__ be1,
    const float* __restrict__ We2,
    const float* __restrict__ Wn1, const float* __restrict__ Wn2,
    unsigned short* __restrict__ WpqT, unsigned short* __restrict__ We2T,
    unsigned short* __restrict__ Wn1T, unsigned short* __restrict__ Wn2T,
    unsigned short* __restrict__ WrT,
    int* __restrict__ cnt)
{
  const int gid = blockIdx.x * 256 + threadIdx.x;
  const int gsz = gridDim.x * 256;
  for (int i = gid; i < 128 * SPQ; i += gsz) {
    int n = i / SPQ, k = i % SPQ;
    unsigned short v = 0;
    if (k < 128) v = (n < 64) ? f2bf(We1[k * 64 + n]) : f2bf(We1[(128 + k) * 64 + (n - 64)]);
    WpqT[i] = v;
  }
  for (int i = gid; i < 64 * SW2; i += gsz) {
    int n = i / SW2, k = i % SW2;
    We2T[i] = (k < 64) ? f2bf(We2[k * 64 + n]) : (unsigned short)0;
  }
  for (int i = gid; i < 256 * SN1; i += gsz) {
    int n = i / SN1, k = i % SN1;
    Wn1T[i] = (k < 192) ? f2bf(Wn1[k * 256 + n]) : (unsigned short)0;
  }
  for (int i = gid; i < 128 * SN2; i += gsz) {
    int n = i / SN2, k = i % SN2;
    Wn2T[i] = (k < 256) ? f2bf(Wn2[k * 128 + n]) : (unsigned short)0;
  }
  for (int i = gid; i < 64 * 32; i += gsz) {
    int n = i >> 5, k = i & 31;
    float v = 0.f;
    if (k < 2)       v = We1[256 * 64 + n];
    else if (k < 4)  v = We1[257 * 64 + n];
    else if (k < 12) v = We1[(258 + (k - 4)) * 64 + n];
    else if (k == 12) v = be1[n];
    else if (k == 13) { float w = We1[256 * 64 + n]; v = w - bf2f(f2bf(w)); }
    else if (k == 14) { float w = We1[257 * 64 + n]; v = w - bf2f(f2bf(w)); }
    else if (k == 15) { float w = be1[n];            v = w - bf2f(f2bf(w)); }
    WrT[i] = (k < 16) ? f2bf(v) : (unsigned short)0;
  }
  if (gid < N_EDGES) atomicAdd(&cnt[eidx[gid]], 1);
}

// ---------------------------------------------------------------------------
// hierarchical scan (coalesced, no per-thread arrays)
// ---------------------------------------------------------------------------
__global__ __launch_bounds__(512) void scan_local(
    const int* __restrict__ cnt, int* __restrict__ rowptr,
    int* __restrict__ bsum)
{
  __shared__ int wsum[8], woff[8];
  const int t = threadIdx.x;
  const int idx = blockIdx.x * 512 + t;
  const int lane = t & 63, wid = t >> 6;
  int c = (idx < N_NODES) ? cnt[idx] : 0;
  int v = c;
  #pragma unroll
  for (int o = 1; o < 64; o <<= 1) {
    int u = __shfl_up(v, o);
    if (lane >= o) v += u;
  }
  if (lane == 63) wsum[wid] = v;
  __syncthreads();
  if (t == 0) {
    int a = 0;
    #pragma unroll
    for (int w = 0; w < 8; ++w) { woff[w] = a; a += wsum[w]; }
    bsum[blockIdx.x] = a;
  }
  __syncthreads();
  if (idx < N_NODES) rowptr[idx] = woff[wid] + (v - c);
}

__global__ __launch_bounds__(128) void scan_mid(
    const int* __restrict__ bsum, int* __restrict__ boff)
{
  __shared__ int ws[2];
  const int t = threadIdx.x;
  const int lane = t & 63, wid = t >> 6;
  int c = (t < SCAN_B) ? bsum[t] : 0;
  int v = c;
  #pragma unroll
  for (int o = 1; o < 64; o <<= 1) {
    int u = __shfl_up(v, o);
    if (lane >= o) v += u;
  }
  if (lane == 63) ws[wid] = v;
  __syncthreads();
  int add = (wid == 1) ? ws[0] : 0;
  if (t < SCAN_B) boff[t] = add + (v - c);
}

// scan_add also zeroes agg (folds the 12.8 MB memset dispatch away)
__global__ __launch_bounds__(512) void scan_add(
    const int* __restrict__ rowptr, const int* __restrict__ boff,
    int* __restrict__ cursor, float4* __restrict__ agg)
{
  const int idx = blockIdx.x * 512 + threadIdx.x;
  if (idx < N_NODES) cursor[idx] = rowptr[idx] + boff[blockIdx.x];
  if (idx < 50048) {
    float4 z = make_float4(0.f, 0.f, 0.f, 0.f);
    float4* p = agg + (long)idx * 16;
    #pragma unroll
    for (int k = 0; k < 16; ++k) p[k] = z;
  }
}

// ---------------------------------------------------------------------------
// fill_reorder: one thread per edge, coalesced reads, gate MLP, ONE 32-B
// record scattered to rec[pos] (plain stores keep rec L2-warm for consumer).
// Record: [0:8) d2h,d2l,dlh,dll  [8:24) struct bf16  [24:28) g  [28:32) i|j<<16
// ---------------------------------------------------------------------------
__global__ void fill_reorder(
    const int* __restrict__ eidx, const float* __restrict__ xyz,
    const float* __restrict__ estruct, const float* __restrict__ erest,
    int* __restrict__ cursor,
    const float* __restrict__ Wg1, const float* __restrict__ bg1,
    const float* __restrict__ Wg2, const float* __restrict__ bg2,
    unsigned short* __restrict__ rec)
{
  int e = blockIdx.x * 256 + threadIdx.x;
  if (e >= N_EDGES) return;
  int i = eidx[e], j = eidx[N_EDGES + e];
  float dx = xyz[i * 3 + 0] - xyz[j * 3 + 0];
  float dy = xyz[i * 3 + 1] - xyz[j * 3 + 1];
  float dz = xyz[i * 3 + 2] - xyz[j * 3 + 2];
  float d2 = dx * dx + dy * dy + dz * dz;
  float dist = sqrtf(d2 + 1e-9f);
  float rest = erest[e];
  float dl = (dist - rest) / (rest + 1e-9f);
  float4 s0 = *(const float4*)&estruct[e * 8];
  float4 s1 = *(const float4*)&estruct[e * 8 + 4];
  float st[8] = {s0.x, s0.y, s0.z, s0.w, s1.x, s1.y, s1.z, s1.w};
  float gsum = 0.f;
  #pragma unroll
  for (int h = 0; h < 32; ++h) {
    float a = bg1[h] + d2 * Wg1[0 * 32 + h] + dl * Wg1[1 * 32 + h];
    #pragma unroll
    for (int c = 0; c < 8; ++c) a += st[c] * Wg1[(2 + c) * 32 + h];
    gsum += silu_f(a) * Wg2[h];
  }
  float g = sigmoid_f(gsum + bg2[0]);

  unsigned short d2h = f2bf(d2);
  unsigned short d2l = f2bf(d2 - bf2f(d2h));
  unsigned short dlh = f2bf(dl);
  unsigned short dll = f2bf(dl - bf2f(dlh));

  ushort8 w0;
  w0[0] = d2h; w0[1] = d2l; w0[2] = dlh; w0[3] = dll;
  w0[4] = f2bf(st[0]); w0[5] = f2bf(st[1]); w0[6] = f2bf(st[2]); w0[7] = f2bf(st[3]);
  uint4v w1;
  w1[0] = (unsigned int)f2bf(st[4]) | ((unsigned int)f2bf(st[5]) << 16);
  w1[1] = (unsigned int)f2bf(st[6]) | ((unsigned int)f2bf(st[7]) << 16);
  w1[2] = __float_as_uint(g);
  w1[3] = (unsigned int)i | ((unsigned int)j << 16);

  int pos = atomicAdd(&cursor[i], 1);
  unsigned short* dst = rec + (long)pos * 16;
  *(uint4v*)dst = *(uint4v*)&w0;
  *(uint4v*)(dst + 8) = w1;
}

// ---------------------------------------------------------------------------
// pq: standalone, LDS-free A-path. Stage only Ws (34.8 KB) + one barrier;
// each of 4 waves computes 16 rows, loading H fragments directly
// (f32 -> pack8 -> Hbf export inline). Grid = NODE_TILES.
// ---------------------------------------------------------------------------
__global__ __launch_bounds__(256, 4) void pq_kernel(
    const float* __restrict__ H, const unsigned short* __restrict__ WpqT,
    unsigned short* __restrict__ P, unsigned short* __restrict__ Q,
    unsigned short* __restrict__ Hbf)
{
  __shared__ unsigned short Ws[128 * SPQ];   // 34.8 KB (only LDS)

  const int tid  = threadIdx.x;
  const int lane = tid & 63;
  const int wv   = tid >> 6;
  const int lr   = lane & 15;
  const int lq   = lane >> 4;
  const int n0   = blockIdx.x * 64;
  const int m0   = wv * 16;

  for (int i = tid * 8; i < 128 * SPQ; i += 256 * 8)
    *(bf16x8*)&Ws[i] = *(const bf16x8*)&WpqT[i];
  __syncthreads();

  const int rowa = n0 + m0 + lr;
  const int rowc = rowa < N_NODES ? rowa : N_NODES - 1;

  f32x4 zero4 = {0.f, 0.f, 0.f, 0.f};
  f32x4 acc[8];
  #pragma unroll
  for (int f = 0; f < 8; ++f) acc[f] = zero4;

  #pragma unroll
  for (int s = 0; s < 4; ++s) {
    int kb = s * 32 + lq * 8;
    const float* p = H + (long)rowc * 128 + kb;
    float4 u = *(const float4*)p;
    float4 v = *(const float4*)(p + 4);
    bf16x8 a = pack8(u, v);
    *(bf16x8*)&Hbf[(long)rowa * 128 + kb] = a;   // export (each (row,kb) once)
    #pragma unroll
    for (int f = 0; f < 8; ++f) {
      bf16x8 b = *(const bf16x8*)&Ws[(f * 16 + lr) * SPQ + kb];
      acc[f] = __builtin_amdgcn_mfma_f32_16x16x32_bf16(a, b, acc[f], 0, 0, 0);
    }
  }
  #pragma unroll
  for (int f = 0; f < 8; ++f) {
    #pragma unroll
    for (int r = 0; r < 4; ++r) {
      int node = n0 + m0 + lq * 4 + r;
      if (node < N_NODES) {
        if (f < 4) P[(long)node * 64 + f * 16 + lr] = f2bf(acc[f][r]);
        else       Q[(long)node * 64 + (f - 4) * 16 + lr] = f2bf(acc[f][r]);
      }
    }
  }
}

// ---------------------------------------------------------------------------
// edge_compute (R18): launch geometry REVERTED to R8-measured best
// (grid 962, chunk 13, launch_bounds(256,4)). R12's grid-1563 experiment
// cost +8.3 MB FETCH (601 extra blocks x 13 KB weight re-staging, evicted
// by the rec stream) and +10 us. Es/message aliasing kept (neutral at
// 4 blk/CU). Ballot segsum unchanged.
// ---------------------------------------------------------------------------
__global__ __launch_bounds__(256, 4) void edge_compute(
    const unsigned short* __restrict__ P, const unsigned short* __restrict__ Q,
    const unsigned short* __restrict__ rec,
    const unsigned short* __restrict__ We2T, const float* __restrict__ be2,
    const unsigned short* __restrict__ WrT,
    float* __restrict__ agg)
{
  __shared__ unsigned short W2s[64 * SW2];       // 9.2 KB
  __shared__ unsigned short Es [4 * 16 * SE];    // 9.2 KB (also message tile)
  __shared__ unsigned short At [4 * 16 * ATS];   // 5.1 KB  (23.5 KB total)

  const int tid  = threadIdx.x;
  const int lane = tid & 63;
  const int wv   = tid >> 6;
  const int lr   = lane & 15;
  const int lq   = lane >> 4;

  for (int i = tid * 8; i < 64 * SW2; i += 256 * 8)
    *(bf16x8*)&W2s[i] = *(const bf16x8*)&We2T[i];

  unsigned short* Es_w = &Es[wv * 16 * SE];
  unsigned short* At_w = &At[wv * 16 * ATS];

  if (lane < 16) {
    ushort8 z;
    #pragma unroll
    for (int c = 0; c < 8; ++c) z[c] = 0;
    *(ushort8*)&At_w[lane * ATS + 16] = z;
    *(ushort8*)&At_w[lane * ATS + 24] = z;
  }

  bf16x8 aWr[4];
  float bias2[4][4];
  #pragma unroll
  for (int f = 0; f < 4; ++f) {
    aWr[f] = *(const bf16x8*)&WrT[(f * 16 + lr) * 32 + lq * 8];
    #pragma unroll
    for (int r = 0; r < 4; ++r) bias2[f][r] = be2[f * 16 + lq * 4 + r];
  }
  __syncthreads();

  const int n_tiles = N_EDGES / 16;  // 50000
  const int wid = blockIdx.x * 4 + wv;
  const int t0 = wid * EC_CHUNK;
  const int t1 = (t0 + EC_CHUNK < n_tiles) ? (t0 + EC_CHUNK) : n_tiles;
  if (t0 >= n_tiles) return;

  f32x4 zero4 = {0.f, 0.f, 0.f, 0.f};
  int   cur_node;
  {
    int ij0 = *(const int*)(rec + (long)t0 * 16 * 16 + 14);
    cur_node = ij0 & 0xffff;
  }
  float acc        = 0.f;
  bool  use_atomic = true;

  for (int tile = t0; tile < t1; ++tile) {
    const int s0 = tile * 16;

    const unsigned short* rp = rec + (long)(s0 + lr) * 16;
    ushort8 ra = *(const ushort8*)rp;          // d2h,d2l,dlh,dll,st0..3
    uint4   rb = *(const uint4*)(rp + 8);      // st4..7 | g | i,j
    float g     = __uint_as_float(rb.z);
    int   inode = (int)(rb.w & 0xffff);
    int   jnode = (int)((rb.w >> 16) & 0xffff);

    if (lane < 16) {
      ushort8 w1;
      w1[0] = (unsigned short)(rb.x & 0xffff);
      w1[1] = (unsigned short)(rb.x >> 16);
      w1[2] = (unsigned short)(rb.y & 0xffff);
      w1[3] = (unsigned short)(rb.y >> 16);
      w1[4] = 0x3F80u; w1[5] = (unsigned short)ra[0];
      w1[6] = (unsigned short)ra[2]; w1[7] = 0x3F80u;
      *(ushort8*)&At_w[lane * ATS]     = ra;
      *(ushort8*)&At_w[lane * ATS + 8] = w1;
    }

    bf16x8 bA = *(const bf16x8*)&At_w[lr * ATS + lq * 8];
    f32x4 acc1[4];
    #pragma unroll
    for (int f = 0; f < 4; ++f)
      acc1[f] = __builtin_amdgcn_mfma_f32_16x16x32_bf16(aWr[f], bA, zero4, 0, 0, 0);

    const unsigned short* Pb = P + (long)inode * 64;
    const unsigned short* Qb = Q + (long)jnode * 64;
    #pragma unroll
    for (int f = 0; f < 4; ++f) {
      short4v pv = *(const short4v*)&Pb[f * 16 + lq * 4];
      short4v qv = *(const short4v*)&Qb[f * 16 + lq * 4];
      float v0 = silu_f(bf2f((unsigned short)pv[0]) + bf2f((unsigned short)qv[0]) + acc1[f][0]);
      float v1 = silu_f(bf2f((unsigned short)pv[1]) + bf2f((unsigned short)qv[1]) + acc1[f][1]);
      float v2 = silu_f(bf2f((unsigned short)pv[2]) + bf2f((unsigned short)qv[2]) + acc1[f][2]);
      float v3 = silu_f(bf2f((unsigned short)pv[3]) + bf2f((unsigned short)qv[3]) + acc1[f][3]);
      uint2 w;
      w.x = cvt_pk_bf16(v0, v1);
      w.y = cvt_pk_bf16(v2, v3);
      *(uint2*)&Es_w[lr * SE + f * 16 + lq * 4] = w;
    }

    f32x4 acc2[4];
    #pragma unroll
    for (int f = 0; f < 4; ++f) acc2[f] = zero4;
    #pragma unroll
    for (int s = 0; s < 2; ++s) {
      int kb = s * 32 + lq * 8;
      bf16x8 bE = *(const bf16x8*)&Es_w[lr * SE + kb];
      #pragma unroll
      for (int f = 0; f < 4; ++f) {
        bf16x8 aW = *(const bf16x8*)&W2s[(f * 16 + lr) * SW2 + kb];
        acc2[f] = __builtin_amdgcn_mfma_f32_16x16x32_bf16(aW, bE, acc2[f], 0, 0, 0);
      }
    }

    // epilogue: silu+gate -> message tile (ALIASES Es; GEMM2 already consumed)
    #pragma unroll
    for (int f = 0; f < 4; ++f) {
      float o0 = silu_f(acc2[f][0] + bias2[f][0]) * g;
      float o1 = silu_f(acc2[f][1] + bias2[f][1]) * g;
      float o2 = silu_f(acc2[f][2] + bias2[f][2]) * g;
      float o3 = silu_f(acc2[f][3] + bias2[f][3]) * g;
      uint2 w;
      w.x = cvt_pk_bf16(o0, o1);
      w.y = cvt_pk_bf16(o2, o3);
      *(uint2*)&Es_w[lr * SE + f * 16 + lq * 4] = w;
    }

    // segmented sum: hoisted reads + ballot boundary mask (SGPR control)
    float mv[16];
    #pragma unroll
    for (int e = 0; e < 16; ++e) mv[e] = bf2f(Es_w[e * SE + lane]);

    int up = __shfl_up(inode, 1);
    unsigned long long bm = __ballot(inode != up);
    unsigned mask = (unsigned)bm & 0xFFFEu;
    int i0 = __builtin_amdgcn_readlane(inode, 0);
    if (i0 != cur_node) mask |= 1u;

    #pragma unroll
    for (int e = 0; e < 16; ++e) {
      if (mask & (1u << e)) {
        if (use_atomic) atomicAdd(&agg[(long)cur_node * 64 + lane], acc);
        else            agg[(long)cur_node * 64 + lane] = acc;
        use_atomic = false;
        cur_node = __builtin_amdgcn_readlane(inode, e);
        acc = 0.f;
      }
      acc += mv[e];
    }
  }
  atomicAdd(&agg[(long)cur_node * 64 + lane], acc);
}

// ---------------------------------------------------------------------------
// h1_kernel: h1 = silu([Hbf|agg] @ Wn1 + bn1) -> global bf16. Half of Wn1T
// LDS-resident per block (55.3 KB), persistent loop.
// ---------------------------------------------------------------------------
__global__ __launch_bounds__(256, 2) void h1_kernel(
    const unsigned short* __restrict__ Hbf, const float* __restrict__ agg,
    const unsigned short* __restrict__ Wn1T, const float* __restrict__ bn1,
    unsigned short* __restrict__ h1)
{
  __shared__ unsigned short Wl[128 * SN1];   // 55.3 KB

  const int tid  = threadIdx.x;
  const int lane = tid & 63;
  const int wv   = tid >> 6;
  const int lr   = lane & 15;
  const int lq   = lane >> 4;
  const int m0   = wv * 16;
  const int p    = blockIdx.x & 1;           // which 128-col half

  for (int i = tid * 8; i < 128 * SN1; i += 256 * 8)
    *(bf16x8*)&Wl[i] = *(const bf16x8*)&Wn1T[p * 128 * SN1 + i];
  __syncthreads();

  f32x4 zero4 = {0.f, 0.f, 0.f, 0.f};
  for (int t = blockIdx.x >> 1; t < NODE_TILES; t += 256) {
    const int n0 = t * 64;
    int rowa = n0 + m0 + lr;
    int rowc = rowa < N_NODES ? rowa : N_NODES - 1;

    f32x4 acc1[8];
    #pragma unroll
    for (int f = 0; f < 8; ++f) acc1[f] = zero4;
    #pragma unroll
    for (int s = 0; s < 6; ++s) {
      int kb = s * 32 + lq * 8;
      bf16x8 a;
      if (s < 4) {
        a = *(const bf16x8*)&Hbf[(long)rowa * 128 + kb];
      } else {
        const float* pp = agg + (long)rowc * 64 + (kb - 128);
        float4 u = *(const float4*)pp;
        float4 v = *(const float4*)(pp + 4);
        a = pack8(u, v);
      }
      #pragma unroll
      for (int f = 0; f < 8; ++f) {
        bf16x8 b = *(const bf16x8*)&Wl[(f * 16 + lr) * SN1 + kb];
        acc1[f] = __builtin_amdgcn_mfma_f32_16x16x32_bf16(a, b, acc1[f], 0, 0, 0);
      }
    }
    #pragma unroll
    for (int f = 0; f < 8; ++f) {
      int col = p * 128 + f * 16 + lr;
      float bias = bn1[col];
      #pragma unroll
      for (int r = 0; r < 4; ++r) {
        int node = n0 + m0 + lq * 4 + r;
        h1[(long)node * 256 + col] = f2bf(silu_f(acc1[f][r] + bias));
      }
    }
  }
}

// ---------------------------------------------------------------------------
// out_kernel: upd = h1 @ Wn2 + bn2; out = LN(H + upd). Wn2T LDS-resident.
// ---------------------------------------------------------------------------
__global__ __launch_bounds__(256, 2) void out_kernel(
    const float* __restrict__ H, const unsigned short* __restrict__ h1,
    const unsigned short* __restrict__ Wn2T, const float* __restrict__ bn2,
    const float* __restrict__ ln_g, const float* __restrict__ ln_b,
    float* __restrict__ out)
{
  __shared__ unsigned short Wl[128 * SN2];   // 71.7 KB

  const int tid  = threadIdx.x;
  const int lane = tid & 63;
  const int wv   = tid >> 6;
  const int lr   = lane & 15;
  const int lq   = lane >> 4;
  const int m0   = wv * 16;

  for (int i = tid * 8; i < 128 * SN2; i += 256 * 8)
    *(bf16x8*)&Wl[i] = *(const bf16x8*)&Wn2T[i];
  __syncthreads();

  f32x4 zero4 = {0.f, 0.f, 0.f, 0.f};
  for (int t = blockIdx.x; t < NODE_TILES; t += 512) {
    const int n0 = t * 64;
    int rowa = n0 + m0 + lr;

    f32x4 acc2[8];
    #pragma unroll
    for (int f = 0; f < 8; ++f) acc2[f] = zero4;
    #pragma unroll
    for (int s = 0; s < 8; ++s) {
      int kb = s * 32 + lq * 8;
      bf16x8 a = *(const bf16x8*)&h1[(long)rowa * 256 + kb];
      #pragma unroll
      for (int f = 0; f < 8; ++f) {
        bf16x8 b = *(const bf16x8*)&Wl[(f * 16 + lr) * SN2 + kb];
        acc2[f] = __builtin_amdgcn_mfma_f32_16x16x32_bf16(a, b, acc2[f], 0, 0, 0);
      }
    }

    #pragma unroll
    for (int r = 0; r < 4; ++r) {
      int node = n0 + m0 + lq * 4 + r;
      int nc = node < N_NODES ? node : N_NODES - 1;
      float x[8];
      float sum = 0.f, sumsq = 0.f;
      #pragma unroll
      for (int f = 0; f < 8; ++f) {
        int n = f * 16 + lr;
        float u = acc2[f][r] + bn2[n];
        float xv = H[(long)nc * 128 + n] + u;
        x[f] = xv;
        sum += xv;
        sumsq += xv * xv;
      }
      #pragma unroll
      for (int o = 1; o < 16; o <<= 1) {
        sum   += __shfl_xor(sum, o);
        sumsq += __shfl_xor(sumsq, o);
      }
      float mu  = sum * (1.f / 128.f);
      float var = sumsq * (1.f / 128.f) - mu * mu;
      float rstd = rsqrtf(var + 1e-5f);
      if (node < N_NODES) {
        #pragma unroll
        for (int f = 0; f < 8; ++f) {
          int n = f * 16 + lr;
          out[(long)node * 128 + n] = (x[f] - mu) * rstd * ln_g[n] + ln_b[n];
        }
      }
    }
  }
}

extern "C" void kernel_launch(void* const* d_in, const int* in_sizes, int n_in,
                              void* d_out, int out_size, void* d_ws, size_t ws_size,
                              hipStream_t stream) {
  const float* H       = (const float*)d_in[0];
  const float* xyz     = (const float*)d_in[1];
  const int*   eidx    = (const int*)d_in[2];
  const float* estruct = (const float*)d_in[3];
  const float* erest   = (const float*)d_in[4];
  const float* We1     = (const float*)d_in[5];
  const float* be1     = (const float*)d_in[6];
  const float* We2     = (const float*)d_in[7];
  const float* be2     = (const float*)d_in[8];
  const float* Wg1     = (const float*)d_in[9];
  const float* bg1     = (const float*)d_in[10];
  const float* Wg2     = (const float*)d_in[11];
  const float* bg2     = (const float*)d_in[12];
  const float* Wn1     = (const float*)d_in[13];
  const float* bn1     = (const float*)d_in[14];
  const float* Wn2     = (const float*)d_in[15];
  const float* bn2     = (const float*)d_in[16];
  const float* ln_g    = (const float*)d_in[17];
  const float* ln_b    = (const float*)d_in[18];

  char* ws = (char*)d_ws;
  float*          agg    = (float*)(ws + 0);                    //  12,812,288 (50048*64*4)
  unsigned short* Hbf    = (unsigned short*)(ws + 12812288);    //  12,812,288 (50048*128*2)
  unsigned short* rec    = (unsigned short*)(ws + 25624576);    //  25,600,000 (800000*32, slot-indexed)
  unsigned short* P      = (unsigned short*)(ws + 51224576);    //   6,400,000
  unsigned short* Qm     = (unsigned short*)(ws + 57624576);    //   6,400,000
  int*            cnt    = (int*)(ws + 64024576);               //     200,192
  int*            rowptr = (int*)(ws + 64224768);               //     200,192 (scan temp)
  int*            cursor = (int*)(ws + 64424960);               //     200,192
  unsigned short* WpqT   = (unsigned short*)(ws + 64625152);    //      34,816
  unsigned short* We2T   = (unsigned short*)(ws + 64659968);    //       9,216
  unsigned short* Wn1T   = (unsigned short*)(ws + 64669184);    //     110,592 (256*216)
  unsigned short* Wn2T   = (unsigned short*)(ws + 64779776);    //      71,680 (128*280)
  unsigned short* WrT    = (unsigned short*)(ws + 64851456);    //       4,096
  int*            bsum   = (int*)(ws + 64855552);               //         512
  int*            boff   = (int*)(ws + 64856064);               //         512
  unsigned short* h1     = (unsigned short*)(ws + 64856576);    //  25,624,576 (50048*256*2)
  float* out = (float*)d_out;

  hipMemsetAsync(cnt, 0, (size_t)N_NODES * sizeof(int), stream);

  hipLaunchKernelGGL(prep_hist, dim3(3125), dim3(256), 0, stream,
                     eidx, We1, be1, We2, Wn1, Wn2, WpqT, We2T, Wn1T, Wn2T, WrT, cnt);
  hipLaunchKernelGGL(scan_local, dim3(SCAN_B), dim3(512), 0, stream,
                     cnt, rowptr, bsum);
  hipLaunchKernelGGL(scan_mid, dim3(1), dim3(128), 0, stream,
                     bsum, boff);
  hipLaunchKernelGGL(scan_add, dim3(SCAN_B), dim3(512), 0, stream,
                     rowptr, boff, cursor, (float4*)agg);
  hipLaunchKernelGGL(fill_reorder, dim3(3125), dim3(256), 0, stream,
                     eidx, xyz, estruct, erest, cursor,
                     Wg1, bg1, Wg2, bg2, rec);
  hipLaunchKernelGGL(pq_kernel, dim3(NODE_TILES), dim3(256), 0, stream,
                     H, WpqT, P, Qm, Hbf);
  hipLaunchKernelGGL(edge_compute, dim3(EC_GRID), dim3(256), 0, stream,
                     P, Qm, rec, We2T, be2, WrT, agg);
  hipLaunchKernelGGL(h1_kernel, dim3(512), dim3(256), 0, stream,
                     Hbf, agg, Wn1T, bn1, h1);
  hipLaunchKernelGGL(out_kernel, dim3(512), dim3(256), 0, stream,
                     H, h1, Wn2T, bn2, ln_g, ln_b, out);
}